// Round 1
// baseline (1266.361 us; speedup 1.0000x reference)
//
#include <hip/hip_runtime.h>
#include <math.h>

#define NB  64
#define NLQ 1024
#define NLK 1024
#define ND  128

// 1/sqrt(128)
constexpr float kInvTemp = 0.08838834764831845f;

// ---------------- mask dtype probe ----------------
// Writes flag=1 if the mask buffer is byte-packed bools, 0 if int32 {0,1}.
// Random 0/1 bytes viewed as u32 words exceed 1 with prob 7/8 per word;
// int32 {0,1} words never do. 4096 words => certainty.
__global__ void mask_probe_kernel(const unsigned int* __restrict__ w,
                                  int* __restrict__ flag) {
    __shared__ int any_big;
    if (threadIdx.x == 0) any_big = 0;
    __syncthreads();
    int bad = 0;
    for (int i = threadIdx.x; i < 4096; i += 256) bad |= (w[i] > 1u) ? 1 : 0;
    if (bad) atomicOr(&any_big, 1);
    __syncthreads();
    if (threadIdx.x == 0) *flag = any_big;
}

// ---------------- K1: S = Q K^T * invTemp ----------------
// grid (LQ/128, LK/128, B), 256 threads, 8x8 micro-tile, depth chunks of 32.
__launch_bounds__(256)
__global__ void qk_kernel(const float* __restrict__ Q, const float* __restrict__ K,
                          float* __restrict__ S) {
    const int b  = blockIdx.z;
    const int q0 = blockIdx.x * 128;
    const int k0 = blockIdx.y * 128;
    const float* Qb = Q + ((size_t)b * NLQ + q0) * ND;
    const float* Kb = K + ((size_t)b * NLK + k0) * ND;

    __shared__ __align__(16) float As[32][132];   // As[d][qrow]
    __shared__ __align__(16) float Bs[32][132];   // Bs[d][krow]

    const int t  = threadIdx.x;
    const int tx = t & 15;
    const int ty = t >> 4;

    float acc[8][8];
#pragma unroll
    for (int i = 0; i < 8; ++i)
#pragma unroll
        for (int j = 0; j < 8; ++j) acc[i][j] = 0.f;

    for (int dk0 = 0; dk0 < ND; dk0 += 32) {
#pragma unroll
        for (int p = 0; p < 4; ++p) {
            int idx = p * 256 + t;        // 1024 float4 slots: 128 rows x 8
            int row = idx >> 3;
            int dc  = (idx & 7) << 2;
            float4 qa = *(const float4*)(Qb + (size_t)row * ND + dk0 + dc);
            As[dc + 0][row] = qa.x; As[dc + 1][row] = qa.y;
            As[dc + 2][row] = qa.z; As[dc + 3][row] = qa.w;
            float4 kb = *(const float4*)(Kb + (size_t)row * ND + dk0 + dc);
            Bs[dc + 0][row] = kb.x; Bs[dc + 1][row] = kb.y;
            Bs[dc + 2][row] = kb.z; Bs[dc + 3][row] = kb.w;
        }
        __syncthreads();
#pragma unroll 4
        for (int d = 0; d < 32; ++d) {
            float a8[8], b8[8];
            *(float4*)&a8[0] = *(const float4*)&As[d][ty * 8 + 0];
            *(float4*)&a8[4] = *(const float4*)&As[d][ty * 8 + 4];
            *(float4*)&b8[0] = *(const float4*)&Bs[d][tx * 8 + 0];
            *(float4*)&b8[4] = *(const float4*)&Bs[d][tx * 8 + 4];
#pragma unroll
            for (int i = 0; i < 8; ++i)
#pragma unroll
                for (int j = 0; j < 8; ++j)
                    acc[i][j] = fmaf(a8[i], b8[j], acc[i][j]);
        }
        __syncthreads();
    }

#pragma unroll
    for (int i = 0; i < 8; ++i) {
        float4 v0 = make_float4(acc[i][0] * kInvTemp, acc[i][1] * kInvTemp,
                                acc[i][2] * kInvTemp, acc[i][3] * kInvTemp);
        float4 v1 = make_float4(acc[i][4] * kInvTemp, acc[i][5] * kInvTemp,
                                acc[i][6] * kInvTemp, acc[i][7] * kInvTemp);
        float* dst = S + ((size_t)b * NLQ + q0 + ty * 8 + i) * NLK + k0 + tx * 8;
        *(float4*)dst       = v0;
        *(float4*)(dst + 4) = v1;
    }
}

// ---------------- K2: row-wise log_softmax + masked softmax ----------------
// One wave per row (4 rows/block). Reads S from the log_attn slot, writes
// log_attn in place and attn. Mask interpreted per probe flag.
__launch_bounds__(256)
__global__ void softmax_kernel(const int* __restrict__ flag,
                               const void* __restrict__ mask,
                               float* __restrict__ LA, float* __restrict__ AT) {
    const int lane = threadIdx.x & 63;
    const int wv   = threadIdx.x >> 6;
    const size_t row = (size_t)blockIdx.x * 4 + wv;
    float* srow = LA + row * NLK;
    float* arow = AT + row * NLK;

    float s[16];
#pragma unroll
    for (int cc = 0; cc < 4; ++cc) {
        float4 v = *(const float4*)(srow + cc * 256 + lane * 4);
        s[cc * 4 + 0] = v.x; s[cc * 4 + 1] = v.y;
        s[cc * 4 + 2] = v.z; s[cc * 4 + 3] = v.w;
    }

    float m = -3.4e38f;
#pragma unroll
    for (int i = 0; i < 16; ++i) m = fmaxf(m, s[i]);
#pragma unroll
    for (int o = 32; o > 0; o >>= 1) m = fmaxf(m, __shfl_xor(m, o));
    float sum = 0.f;
#pragma unroll
    for (int i = 0; i < 16; ++i) sum += expf(s[i] - m);
#pragma unroll
    for (int o = 32; o > 0; o >>= 1) sum += __shfl_xor(sum, o);
    const float lse = m + logf(sum);

    float p[16];
    const int is_byte = *flag;
    if (is_byte) {
        const unsigned char* mrow = (const unsigned char*)mask + row * NLK;
#pragma unroll
        for (int cc = 0; cc < 4; ++cc) {
            uchar4 mv = *(const uchar4*)(mrow + cc * 256 + lane * 4);
            p[cc * 4 + 0] = mv.x ? -1e9f : s[cc * 4 + 0];
            p[cc * 4 + 1] = mv.y ? -1e9f : s[cc * 4 + 1];
            p[cc * 4 + 2] = mv.z ? -1e9f : s[cc * 4 + 2];
            p[cc * 4 + 3] = mv.w ? -1e9f : s[cc * 4 + 3];
        }
    } else {
        const int* mrow = (const int*)mask + row * NLK;
#pragma unroll
        for (int cc = 0; cc < 4; ++cc) {
            int4 mv = *(const int4*)(mrow + cc * 256 + lane * 4);
            p[cc * 4 + 0] = mv.x ? -1e9f : s[cc * 4 + 0];
            p[cc * 4 + 1] = mv.y ? -1e9f : s[cc * 4 + 1];
            p[cc * 4 + 2] = mv.z ? -1e9f : s[cc * 4 + 2];
            p[cc * 4 + 3] = mv.w ? -1e9f : s[cc * 4 + 3];
        }
    }

    float mm = -3.4e38f;
#pragma unroll
    for (int i = 0; i < 16; ++i) mm = fmaxf(mm, p[i]);
#pragma unroll
    for (int o = 32; o > 0; o >>= 1) mm = fmaxf(mm, __shfl_xor(mm, o));
    float ds = 0.f;
#pragma unroll
    for (int i = 0; i < 16; ++i) { p[i] = expf(p[i] - mm); ds += p[i]; }
#pragma unroll
    for (int o = 32; o > 0; o >>= 1) ds += __shfl_xor(ds, o);
    const float rden = 1.f / ds;

#pragma unroll
    for (int cc = 0; cc < 4; ++cc) {
        float4 la = make_float4(s[cc * 4 + 0] - lse, s[cc * 4 + 1] - lse,
                                s[cc * 4 + 2] - lse, s[cc * 4 + 3] - lse);
        *(float4*)(srow + cc * 256 + lane * 4) = la;
        float4 av = make_float4(p[cc * 4 + 0] * rden, p[cc * 4 + 1] * rden,
                                p[cc * 4 + 2] * rden, p[cc * 4 + 3] * rden);
        *(float4*)(arow + cc * 256 + lane * 4) = av;
    }
}

// ---------------- K3: O = attn * V ----------------
// grid (LQ/128, 1, B), 256 threads, 8x8 micro-tile, depth chunks of 32.
__launch_bounds__(256)
__global__ void pv_kernel(const float* __restrict__ A, const float* __restrict__ V,
                          float* __restrict__ O) {
    const int b  = blockIdx.z;
    const int q0 = blockIdx.x * 128;
    const float* Ab = A + ((size_t)b * NLQ + q0) * NLK;
    const float* Vb = V + (size_t)b * NLK * ND;

    __shared__ __align__(16) float As[32][132];   // As[c][qrow]
    __shared__ __align__(16) float Bs[32][132];   // Bs[c][d]

    const int t  = threadIdx.x;
    const int tx = t & 15;
    const int ty = t >> 4;

    float acc[8][8];
#pragma unroll
    for (int i = 0; i < 8; ++i)
#pragma unroll
        for (int j = 0; j < 8; ++j) acc[i][j] = 0.f;

    for (int c0 = 0; c0 < NLK; c0 += 32) {
#pragma unroll
        for (int p = 0; p < 4; ++p) {
            int idx = p * 256 + t;
            int row = idx >> 3;
            int cc  = (idx & 7) << 2;
            float4 av = *(const float4*)(Ab + (size_t)row * NLK + c0 + cc);
            As[cc + 0][row] = av.x; As[cc + 1][row] = av.y;
            As[cc + 2][row] = av.z; As[cc + 3][row] = av.w;
        }
#pragma unroll
        for (int p = 0; p < 4; ++p) {
            int idx = p * 256 + t;
            int c  = idx >> 5;
            int dc = (idx & 31) << 2;
            *(float4*)&Bs[c][dc] = *(const float4*)(Vb + (size_t)(c0 + c) * ND + dc);
        }
        __syncthreads();
#pragma unroll 4
        for (int c = 0; c < 32; ++c) {
            float a8[8], b8[8];
            *(float4*)&a8[0] = *(const float4*)&As[c][ty * 8 + 0];
            *(float4*)&a8[4] = *(const float4*)&As[c][ty * 8 + 4];
            *(float4*)&b8[0] = *(const float4*)&Bs[c][tx * 8 + 0];
            *(float4*)&b8[4] = *(const float4*)&Bs[c][tx * 8 + 4];
#pragma unroll
            for (int i = 0; i < 8; ++i)
#pragma unroll
                for (int j = 0; j < 8; ++j)
                    acc[i][j] = fmaf(a8[i], b8[j], acc[i][j]);
        }
        __syncthreads();
    }

#pragma unroll
    for (int i = 0; i < 8; ++i) {
        float4 v0 = make_float4(acc[i][0], acc[i][1], acc[i][2], acc[i][3]);
        float4 v1 = make_float4(acc[i][4], acc[i][5], acc[i][6], acc[i][7]);
        float* dst = O + ((size_t)b * NLQ + q0 + ty * 8 + i) * ND + tx * 8;
        *(float4*)dst       = v0;
        *(float4*)(dst + 4) = v1;
    }
}

extern "C" void kernel_launch(void* const* d_in, const int* in_sizes, int n_in,
                              void* d_out, int out_size, void* d_ws, size_t ws_size,
                              hipStream_t stream) {
    (void)in_sizes; (void)n_in; (void)out_size; (void)ws_size;
    const float* q = (const float*)d_in[0];
    const float* k = (const float*)d_in[1];
    const float* v = (const float*)d_in[2];
    const void* mask = d_in[3];

    float* out_o  = (float*)d_out;                              // [B,LQ,D]
    float* out_at = out_o  + (size_t)NB * NLQ * ND;             // [B,LQ,LK]
    float* out_la = out_at + (size_t)NB * NLQ * NLK;            // [B,LQ,LK]

    int* flag = (int*)d_ws;

    mask_probe_kernel<<<1, 256, 0, stream>>>((const unsigned int*)mask, flag);
    qk_kernel<<<dim3(8, 8, NB), 256, 0, stream>>>(q, k, out_la);
    softmax_kernel<<<(NB * NLQ) / 4, 256, 0, stream>>>(flag, mask, out_la, out_at);
    pv_kernel<<<dim3(8, 1, NB), 256, 0, stream>>>(out_at, v, out_o);
}

// Round 2
// 1011.723 us; speedup vs baseline: 1.2517x; 1.2517x over previous
//
#include <hip/hip_runtime.h>
#include <math.h>

#define NB  64
#define NLQ 1024
#define NLK 1024
#define ND  128

constexpr float kInvTemp = 0.08838834764831845f;   // 1/sqrt(128)

typedef __attribute__((ext_vector_type(8))) short short8v;   // 8 bf16 (4 VGPRs)
typedef __attribute__((ext_vector_type(4))) float f32x4;     // MFMA C/D
typedef __attribute__((ext_vector_type(2))) unsigned int u32x2;

// ---- fp32 -> (bf16 hi, bf16 lo) split of 4 consecutive floats.
// Truncating split: hi = bits&0xFFFF0000, lo = trunc(x - hi). lo absorbs hi's
// truncation error so the pair carries ~16 mantissa bits; only the dropped
// lo*lo MFMA term (~2^-16 rel) remains.  ~3 VALU/elem.
__device__ __forceinline__ void split4(const float* __restrict__ p,
                                       u32x2& h, u32x2& l) {
    float4 v = *(const float4*)p;
    unsigned b0 = __float_as_uint(v.x), b1 = __float_as_uint(v.y),
             b2 = __float_as_uint(v.z), b3 = __float_as_uint(v.w);
    float r0 = v.x - __uint_as_float(b0 & 0xFFFF0000u);
    float r1 = v.y - __uint_as_float(b1 & 0xFFFF0000u);
    float r2 = v.z - __uint_as_float(b2 & 0xFFFF0000u);
    float r3 = v.w - __uint_as_float(b3 & 0xFFFF0000u);
    // {hi16(b0), hi16(b1)} little-endian packed
    h.x = __builtin_amdgcn_perm(b1, b0, 0x07060302u);
    h.y = __builtin_amdgcn_perm(b3, b2, 0x07060302u);
    l.x = __builtin_amdgcn_perm(__float_as_uint(r1), __float_as_uint(r0), 0x07060302u);
    l.y = __builtin_amdgcn_perm(__float_as_uint(r3), __float_as_uint(r2), 0x07060302u);
}

// LDS byte offset for a [128 rows][64 cols] bf16 tile, XOR-swizzled so that
// column-slice reads (16 lanes at same col, consecutive rows) are 2-way max.
__device__ __forceinline__ unsigned swz(int row, int colByte) {
    return (unsigned)((row << 7) + colByte) ^ (unsigned)((row & 7) << 4);
}

// ---------------- mask dtype probe ----------------
__global__ void mask_probe_kernel(const unsigned int* __restrict__ w,
                                  int* __restrict__ flag) {
    __shared__ int any_big;
    if (threadIdx.x == 0) any_big = 0;
    __syncthreads();
    int bad = 0;
    for (int i = threadIdx.x; i < 4096; i += 256) bad |= (w[i] > 1u) ? 1 : 0;
    if (bad) atomicOr(&any_big, 1);
    __syncthreads();
    if (threadIdx.x == 0) *flag = any_big;
}

// ---------------- V transpose + split:  Vt[b][d][k] (bf16 hi/lo) ----------------
__launch_bounds__(256)
__global__ void vtrans_kernel(const float* __restrict__ V,
                              short* __restrict__ VtH, short* __restrict__ VtL) {
    const int dt = blockIdx.x;          // d-tile (2 x 64)
    const int kt = blockIdx.y;          // k-tile (16 x 64)
    const int b  = blockIdx.z;
    const float* Vb = V + ((size_t)b * NLK + kt * 64) * ND + dt * 64;
    __shared__ unsigned sh[64][65];     // word = hi<<16 | lo
    const int t = threadIdx.x;
#pragma unroll
    for (int p = 0; p < 4; ++p) {
        const int idx = p * 256 + t;    // 64 k-rows x 16 slots of 4 d
        const int kr  = idx >> 4;
        const int c4  = (idx & 15) << 2;
        float4 v = *(const float4*)(Vb + (size_t)kr * ND + c4);
#pragma unroll
        for (int j = 0; j < 4; ++j) {
            float x = (&v.x)[j];
            unsigned bx = __float_as_uint(x);
            float r = x - __uint_as_float(bx & 0xFFFF0000u);
            sh[kr][c4 + j] = (bx & 0xFFFF0000u) | (__float_as_uint(r) >> 16);
        }
    }
    __syncthreads();
#pragma unroll
    for (int p = 0; p < 4; ++p) {
        const int idx = p * 256 + t;    // 64 d-rows x 16 slots of 4 k
        const int dr  = idx >> 4;
        const int c4  = (idx & 15) << 2;
        unsigned w0 = sh[c4 + 0][dr], w1 = sh[c4 + 1][dr],
                 w2 = sh[c4 + 2][dr], w3 = sh[c4 + 3][dr];
        u32x2 h, l;
        h.x = __builtin_amdgcn_perm(w1, w0, 0x07060302u);
        h.y = __builtin_amdgcn_perm(w3, w2, 0x07060302u);
        l.x = __builtin_amdgcn_perm(w1, w0, 0x05040100u);
        l.y = __builtin_amdgcn_perm(w3, w2, 0x05040100u);
        size_t o = ((size_t)b * ND + dt * 64 + dr) * NLK + kt * 64 + c4;
        *(u32x2*)(VtH + o) = h;
        *(u32x2*)(VtL + o) = l;
    }
}

// ---------------- K1: S = Q K^T * invTemp  (bf16-split MFMA) ----------------
// 128x128 tile, 4 waves each 64x64 (4x4 frags of 16x16x32), BK=64.
__launch_bounds__(256, 2)
__global__ void qk_mfma_kernel(const float* __restrict__ Q,
                               const float* __restrict__ K,
                               float* __restrict__ S) {
    const int bid = blockIdx.x;
    const int b   = bid & 63;           // consecutive bids = consecutive batches -> XCD owns batches b%8
    const int t6  = bid >> 6;
    const int k0  = (t6 & 7) * 128;
    const int q0  = (t6 >> 3) * 128;

    const float* Qb = Q + ((size_t)b * NLQ + q0) * ND;
    const float* Kb = K + ((size_t)b * NLK + k0) * ND;

    __shared__ __align__(16) char lds[65536];
    char* qhi = lds;
    char* qlo = lds + 16384;
    char* khi = lds + 32768;
    char* klo = lds + 49152;

    const int t    = threadIdx.x;
    const int lane = t & 63;
    const int w    = t >> 6;
    const int mb   = (w & 1) * 64;
    const int nb   = (w >> 1) * 64;
    const int lrow = lane & 15;
    const int lg   = lane >> 4;

    f32x4 acc[4][4] = {};

    for (int dk0 = 0; dk0 < ND; dk0 += 64) {
        if (dk0) __syncthreads();
#pragma unroll
        for (int p = 0; p < 8; ++p) {
            const int idx = p * 256 + t;          // 128 rows x 16 slots of 4
            const int row = idx >> 4;
            const int c4  = (idx & 15) << 2;
            const unsigned off = swz(row, c4 << 1);
            u32x2 h, l;
            split4(Qb + (size_t)row * ND + dk0 + c4, h, l);
            *(u32x2*)(qhi + off) = h;
            *(u32x2*)(qlo + off) = l;
            split4(Kb + (size_t)row * ND + dk0 + c4, h, l);
            *(u32x2*)(khi + off) = h;
            *(u32x2*)(klo + off) = l;
        }
        __syncthreads();
#pragma unroll
        for (int kk = 0; kk < 64; kk += 32) {
            const int cb = (kk + lg * 8) << 1;
            short8v ah[4], al[4], bh[4], bl[4];
#pragma unroll
            for (int mi = 0; mi < 4; ++mi) {
                const unsigned off = swz(mb + mi * 16 + lrow, cb);
                ah[mi] = *(const short8v*)(qhi + off);
                al[mi] = *(const short8v*)(qlo + off);
            }
#pragma unroll
            for (int ni = 0; ni < 4; ++ni) {
                const unsigned off = swz(nb + ni * 16 + lrow, cb);
                bh[ni] = *(const short8v*)(khi + off);
                bl[ni] = *(const short8v*)(klo + off);
            }
#pragma unroll
            for (int mi = 0; mi < 4; ++mi)
#pragma unroll
                for (int ni = 0; ni < 4; ++ni) {
                    acc[mi][ni] = __builtin_amdgcn_mfma_f32_16x16x32_bf16(ah[mi], bh[ni], acc[mi][ni], 0, 0, 0);
                    acc[mi][ni] = __builtin_amdgcn_mfma_f32_16x16x32_bf16(ah[mi], bl[ni], acc[mi][ni], 0, 0, 0);
                    acc[mi][ni] = __builtin_amdgcn_mfma_f32_16x16x32_bf16(al[mi], bh[ni], acc[mi][ni], 0, 0, 0);
                }
        }
    }

    float* Sb = S + ((size_t)b * NLQ + q0) * NLK + k0;
#pragma unroll
    for (int mi = 0; mi < 4; ++mi)
#pragma unroll
        for (int ni = 0; ni < 4; ++ni) {
            const int col = nb + ni * 16 + lrow;
            const f32x4 a = acc[mi][ni];
#pragma unroll
            for (int r = 0; r < 4; ++r) {
                const int row = mb + mi * 16 + lg * 4 + r;   // C/D: col=lane&15, row=(lane>>4)*4+reg
                Sb[(size_t)row * NLK + col] = a[r] * kInvTemp;
            }
        }
}

// ---------------- K2: row-wise log_softmax + masked softmax ----------------
__launch_bounds__(256)
__global__ void softmax_kernel(const int* __restrict__ flag,
                               const void* __restrict__ mask,
                               float* __restrict__ LA, float* __restrict__ AT) {
    const int lane = threadIdx.x & 63;
    const int wv   = threadIdx.x >> 6;
    const size_t row = (size_t)blockIdx.x * 4 + wv;
    float* srow = LA + row * NLK;
    float* arow = AT + row * NLK;

    float s[16];
#pragma unroll
    for (int cc = 0; cc < 4; ++cc) {
        float4 v = *(const float4*)(srow + cc * 256 + lane * 4);
        s[cc * 4 + 0] = v.x; s[cc * 4 + 1] = v.y;
        s[cc * 4 + 2] = v.z; s[cc * 4 + 3] = v.w;
    }

    float m = -3.4e38f;
#pragma unroll
    for (int i = 0; i < 16; ++i) m = fmaxf(m, s[i]);
#pragma unroll
    for (int o = 32; o > 0; o >>= 1) m = fmaxf(m, __shfl_xor(m, o));
    float sum = 0.f;
#pragma unroll
    for (int i = 0; i < 16; ++i) sum += expf(s[i] - m);
#pragma unroll
    for (int o = 32; o > 0; o >>= 1) sum += __shfl_xor(sum, o);
    const float lse = m + logf(sum);

    float p[16];
    const int is_byte = *flag;
    if (is_byte) {
        const unsigned char* mrow = (const unsigned char*)mask + row * NLK;
#pragma unroll
        for (int cc = 0; cc < 4; ++cc) {
            uchar4 mv = *(const uchar4*)(mrow + cc * 256 + lane * 4);
            p[cc * 4 + 0] = mv.x ? -1e9f : s[cc * 4 + 0];
            p[cc * 4 + 1] = mv.y ? -1e9f : s[cc * 4 + 1];
            p[cc * 4 + 2] = mv.z ? -1e9f : s[cc * 4 + 2];
            p[cc * 4 + 3] = mv.w ? -1e9f : s[cc * 4 + 3];
        }
    } else {
        const int* mrow = (const int*)mask + row * NLK;
#pragma unroll
        for (int cc = 0; cc < 4; ++cc) {
            int4 mv = *(const int4*)(mrow + cc * 256 + lane * 4);
            p[cc * 4 + 0] = mv.x ? -1e9f : s[cc * 4 + 0];
            p[cc * 4 + 1] = mv.y ? -1e9f : s[cc * 4 + 1];
            p[cc * 4 + 2] = mv.z ? -1e9f : s[cc * 4 + 2];
            p[cc * 4 + 3] = mv.w ? -1e9f : s[cc * 4 + 3];
        }
    }

    float mm = -3.4e38f;
#pragma unroll
    for (int i = 0; i < 16; ++i) mm = fmaxf(mm, p[i]);
#pragma unroll
    for (int o = 32; o > 0; o >>= 1) mm = fmaxf(mm, __shfl_xor(mm, o));
    float ds = 0.f;
#pragma unroll
    for (int i = 0; i < 16; ++i) { p[i] = expf(p[i] - mm); ds += p[i]; }
#pragma unroll
    for (int o = 32; o > 0; o >>= 1) ds += __shfl_xor(ds, o);
    const float rden = 1.f / ds;

#pragma unroll
    for (int cc = 0; cc < 4; ++cc) {
        float4 la = make_float4(s[cc * 4 + 0] - lse, s[cc * 4 + 1] - lse,
                                s[cc * 4 + 2] - lse, s[cc * 4 + 3] - lse);
        *(float4*)(srow + cc * 256 + lane * 4) = la;
        float4 av = make_float4(p[cc * 4 + 0] * rden, p[cc * 4 + 1] * rden,
                                p[cc * 4 + 2] * rden, p[cc * 4 + 3] * rden);
        *(float4*)(arow + cc * 256 + lane * 4) = av;
    }
}

// ---------------- K3: O = attn * V  (bf16-split MFMA, Vt pre-split) ----------------
__launch_bounds__(256, 2)
__global__ void pv_mfma_kernel(const float* __restrict__ A,
                               const short* __restrict__ VtH,
                               const short* __restrict__ VtL,
                               float* __restrict__ O) {
    const int bid = blockIdx.x;
    const int b   = bid & 63;
    const int q0  = (bid >> 6) * 128;

    const float* Ab  = A   + ((size_t)b * NLQ + q0) * NLK;
    const short* VHb = VtH + (size_t)b * ND * NLK;
    const short* VLb = VtL + (size_t)b * ND * NLK;

    __shared__ __align__(16) char lds[65536];
    char* ahi = lds;
    char* alo = lds + 16384;
    char* vhi = lds + 32768;
    char* vlo = lds + 49152;

    const int t    = threadIdx.x;
    const int lane = t & 63;
    const int w    = t >> 6;
    const int mb   = (w & 1) * 64;
    const int nb   = (w >> 1) * 64;
    const int lrow = lane & 15;
    const int lg   = lane >> 4;

    f32x4 acc[4][4] = {};

    for (int c0 = 0; c0 < NLK; c0 += 64) {
        if (c0) __syncthreads();
#pragma unroll
        for (int p = 0; p < 8; ++p) {               // attn: 128 rows x 64 cols fp32 -> split
            const int idx = p * 256 + t;
            const int row = idx >> 4;
            const int c4  = (idx & 15) << 2;
            const unsigned off = swz(row, c4 << 1);
            u32x2 h, l;
            split4(Ab + (size_t)row * NLK + c0 + c4, h, l);
            *(u32x2*)(ahi + off) = h;
            *(u32x2*)(alo + off) = l;
        }
#pragma unroll
        for (int p = 0; p < 4; ++p) {               // Vt: 128 d-rows x 64 k-cols bf16 direct
            const int idx = p * 256 + t;
            const int row = idx >> 3;
            const int c8  = (idx & 7) << 3;
            const unsigned off = swz(row, c8 << 1);
            *(short8v*)(vhi + off) = *(const short8v*)(VHb + (size_t)row * NLK + c0 + c8);
            *(short8v*)(vlo + off) = *(const short8v*)(VLb + (size_t)row * NLK + c0 + c8);
        }
        __syncthreads();
#pragma unroll
        for (int kk = 0; kk < 64; kk += 32) {
            const int cb = (kk + lg * 8) << 1;
            short8v ah[4], al[4], bh[4], bl[4];
#pragma unroll
            for (int mi = 0; mi < 4; ++mi) {
                const unsigned off = swz(mb + mi * 16 + lrow, cb);
                ah[mi] = *(const short8v*)(ahi + off);
                al[mi] = *(const short8v*)(alo + off);
            }
#pragma unroll
            for (int ni = 0; ni < 4; ++ni) {
                const unsigned off = swz(nb + ni * 16 + lrow, cb);
                bh[ni] = *(const short8v*)(vhi + off);
                bl[ni] = *(const short8v*)(vlo + off);
            }
#pragma unroll
            for (int mi = 0; mi < 4; ++mi)
#pragma unroll
                for (int ni = 0; ni < 4; ++ni) {
                    acc[mi][ni] = __builtin_amdgcn_mfma_f32_16x16x32_bf16(ah[mi], bh[ni], acc[mi][ni], 0, 0, 0);
                    acc[mi][ni] = __builtin_amdgcn_mfma_f32_16x16x32_bf16(ah[mi], bl[ni], acc[mi][ni], 0, 0, 0);
                    acc[mi][ni] = __builtin_amdgcn_mfma_f32_16x16x32_bf16(al[mi], bh[ni], acc[mi][ni], 0, 0, 0);
                }
        }
    }

    float* Ob = O + ((size_t)b * NLQ + q0) * ND;
#pragma unroll
    for (int mi = 0; mi < 4; ++mi)
#pragma unroll
        for (int ni = 0; ni < 4; ++ni) {
            const int col = nb + ni * 16 + lrow;
            const f32x4 a = acc[mi][ni];
#pragma unroll
            for (int r = 0; r < 4; ++r) {
                const int row = mb + mi * 16 + lg * 4 + r;
                Ob[(size_t)row * ND + col] = a[r];
            }
        }
}

// ---------------- fallback fp32 PV (used only if ws too small) ----------------
__launch_bounds__(256)
__global__ void pv_fp32_kernel(const float* __restrict__ A, const float* __restrict__ V,
                               float* __restrict__ O) {
    const int b  = blockIdx.z;
    const int q0 = blockIdx.x * 128;
    const float* Ab = A + ((size_t)b * NLQ + q0) * NLK;
    const float* Vb = V + (size_t)b * NLK * ND;

    __shared__ __align__(16) float As[32][132];
    __shared__ __align__(16) float Bs[32][132];

    const int t  = threadIdx.x;
    const int tx = t & 15;
    const int ty = t >> 4;

    float acc[8][8];
#pragma unroll
    for (int i = 0; i < 8; ++i)
#pragma unroll
        for (int j = 0; j < 8; ++j) acc[i][j] = 0.f;

    for (int c0 = 0; c0 < NLK; c0 += 32) {
#pragma unroll
        for (int p = 0; p < 4; ++p) {
            int idx = p * 256 + t;
            int row = idx >> 3;
            int cc  = (idx & 7) << 2;
            float4 av = *(const float4*)(Ab + (size_t)row * NLK + c0 + cc);
            As[cc + 0][row] = av.x; As[cc + 1][row] = av.y;
            As[cc + 2][row] = av.z; As[cc + 3][row] = av.w;
        }
#pragma unroll
        for (int p = 0; p < 4; ++p) {
            int idx = p * 256 + t;
            int c  = idx >> 5;
            int dc = (idx & 31) << 2;
            *(float4*)&Bs[c][dc] = *(const float4*)(Vb + (size_t)(c0 + c) * ND + dc);
        }
        __syncthreads();
#pragma unroll 4
        for (int c = 0; c < 32; ++c) {
            float a8[8], b8[8];
            *(float4*)&a8[0] = *(const float4*)&As[c][ty * 8 + 0];
            *(float4*)&a8[4] = *(const float4*)&As[c][ty * 8 + 4];
            *(float4*)&b8[0] = *(const float4*)&Bs[c][tx * 8 + 0];
            *(float4*)&b8[4] = *(const float4*)&Bs[c][tx * 8 + 4];
#pragma unroll
            for (int i = 0; i < 8; ++i)
#pragma unroll
                for (int j = 0; j < 8; ++j)
                    acc[i][j] = fmaf(a8[i], b8[j], acc[i][j]);
        }
        __syncthreads();
    }

#pragma unroll
    for (int i = 0; i < 8; ++i) {
        float4 v0 = make_float4(acc[i][0], acc[i][1], acc[i][2], acc[i][3]);
        float4 v1 = make_float4(acc[i][4], acc[i][5], acc[i][6], acc[i][7]);
        float* dst = O + ((size_t)b * NLQ + q0 + ty * 8 + i) * ND + tx * 8;
        *(float4*)dst       = v0;
        *(float4*)(dst + 4) = v1;
    }
}

extern "C" void kernel_launch(void* const* d_in, const int* in_sizes, int n_in,
                              void* d_out, int out_size, void* d_ws, size_t ws_size,
                              hipStream_t stream) {
    (void)in_sizes; (void)n_in; (void)out_size;
    const float* q = (const float*)d_in[0];
    const float* k = (const float*)d_in[1];
    const float* v = (const float*)d_in[2];
    const void* mask = d_in[3];

    float* out_o  = (float*)d_out;                              // [B,LQ,D]
    float* out_at = out_o  + (size_t)NB * NLQ * ND;             // [B,LQ,LK]
    float* out_la = out_at + (size_t)NB * NLQ * NLK;            // [B,LQ,LK]

    char* ws   = (char*)d_ws;
    int*  flag = (int*)ws;
    short* VtH = (short*)(ws + 256);
    short* VtL = VtH + (size_t)NB * ND * NLK;
    const size_t need = 256 + 2ull * NB * ND * NLK * sizeof(short);
    const bool fast_pv = ws_size >= need;

    mask_probe_kernel<<<1, 256, 0, stream>>>((const unsigned int*)mask, flag);
    if (fast_pv)
        vtrans_kernel<<<dim3(2, 16, NB), 256, 0, stream>>>(v, VtH, VtL);
    qk_mfma_kernel<<<4096, 256, 0, stream>>>(q, k, out_la);
    softmax_kernel<<<(NB * NLQ) / 4, 256, 0, stream>>>(flag, mask, out_la, out_at);
    if (fast_pv)
        pv_mfma_kernel<<<512, 256, 0, stream>>>(out_at, VtH, VtL, out_o);
    else
        pv_fp32_kernel<<<dim3(8, 1, NB), 256, 0, stream>>>(out_at, v, out_o);
}